// Round 13
// baseline (166.560 us; speedup 1.0000x reference)
//
#include <hip/hip_runtime.h>

#define BB 32
#define MM 512
#define NN 4096
#define KK 4
#define MLO 0.999998f         // 1 - 2^-19: trigger margin, no false negatives
#define FG_BITS 0x3F19999A    // bit pattern of 0.6f

// All IoU values are >= +0.0f, so float ordering == signed-int ordering on the
// bit patterns, with -1 (int) as a below-everything sentinel.

__device__ __forceinline__ int rfl(int x) {
    return __builtin_amdgcn_readfirstlane(x);
}

__device__ __forceinline__ bool beatsI(int v1, int i1, int v2, int i2) {
    // total order: value descending, index ascending (JAX top_k tie-break)
    return (v1 > v2) || (v1 == v2 && i1 < i2);
}

// branchless compare-exchange keeping the winner in (av,ai)
#define CE(av, ai, bv, bi)                                        \
    {                                                             \
        bool _s = beatsI(bv, bi, av, ai);                         \
        int _mv = _s ? bv : av, _nv = _s ? av : bv;               \
        int _mi = _s ? bi : ai, _ni = _s ? ai : bi;               \
        av = _mv; bv = _nv; ai = _mi; bi = _ni;                   \
    }

struct T4 { int v0, v1, v2, v3; int i0, i1, i2, i3; float thr, c1, thrga; };

// ---------------------------------------------------------------------------
// Kernel A: per-gt top-4 (exact JAX top_k tie-break); writes pr_inds/gt_inds
// straight to d_out (count-independent), topv + packed gt data {xyxy, area,
// gmx, gthr} to ws, zeroes counts. Structure = round-11 (best measured):
// 2 gts/wave, no LDS, L2-resident proposal stream with 1-deep prefetch,
// PRIME butterfly + sparse mult-trigger STREAM + parallel-masked-div MERGE.
// ---------------------------------------------------------------------------
__global__ __launch_bounds__(256) void kernA(const float* __restrict__ gt,
                                             const float* __restrict__ pr,
                                             float* __restrict__ topv,
                                             float4* __restrict__ pack,
                                             int* __restrict__ counts,
                                             float* __restrict__ out) {
    const int b = blockIdx.x >> 6;         // 64 blocks per batch (512 gts / 8)
    const int mblk = blockIdx.x & 63;
    const int tid = threadIdx.x;
    const int wave = rfl(tid >> 6), lane = tid & 63;
    const int mbase = mblk * 8 + wave * 2; // 2 gts per wave
    const float4* g4 = (const float4*)(gt + (size_t)b * MM * 4);
    const float4* p4 = (const float4*)(pr + (size_t)b * NN * 4);

#define GTDEF(G) \
    float gx1_##G, gy1_##G, gx2_##G, gy2_##G, ga_##G; \
    { float4 gg = g4[mbase + G]; \
      float x1 = gg.x - 0.5f * gg.z, y1 = gg.y - 0.5f * gg.w; \
      float x2 = gg.x + 0.5f * gg.z, y2 = gg.y + 0.5f * gg.w; \
      gx1_##G = x1; gy1_##G = y1; gx2_##G = x2; gy2_##G = y2; \
      ga_##G = __fmul_rn(x2 - x1, y2 - y1); }

    GTDEF(0) GTDEF(1)

    T4 t0, t1;

    // ---- PRIME (j = 0): exact iou all lanes, butterfly -> uniform top-4 ----
#define PIOU(G, VB) \
    int VB; \
    { float ltx = fmaxf(gx1_##G, px1), lty = fmaxf(gy1_##G, py1); \
      float rbx = fminf(gx2_##G, px2), rby = fminf(gy2_##G, py2); \
      float wc = fmaxf(rbx - ltx, 0.0f), hc = fmaxf(rby - lty, 0.0f); \
      float inter = __fmul_rn(wc, hc); \
      float u = fmaxf((ga_##G + pa) - inter, 1e-9f); \
      VB = __float_as_int(inter / u); }

#define PRIME(T, VB, G) \
    { int x0 = VB, x1 = -1, x2 = -1, x3 = -1; \
      int y0 = lane, y1 = 0x7fffffff, y2 = 0x7fffffff, y3 = 0x7fffffff; \
      for (int off = 1; off < 64; off <<= 1) { \
        int b0 = __shfl_xor(x0, off), b1 = __shfl_xor(x1, off); \
        int b2 = __shfl_xor(x2, off), b3 = __shfl_xor(x3, off); \
        int j0 = __shfl_xor(y0, off), j1 = __shfl_xor(y1, off); \
        int j2 = __shfl_xor(y2, off), j3 = __shfl_xor(y3, off); \
        int z4 = b3, z5 = b2, z6 = b1, z7 = b0; \
        int w4 = j3, w5 = j2, w6 = j1, w7 = j0; \
        CE(x0, y0, z4, w4); CE(x1, y1, z5, w5); \
        CE(x2, y2, z6, w6); CE(x3, y3, z7, w7); \
        CE(x0, y0, x2, y2); CE(x1, y1, x3, y3); \
        CE(x0, y0, x1, y1); CE(x2, y2, x3, y3); \
      } \
      T.v0 = x0; T.v1 = x1; T.v2 = x2; T.v3 = x3; \
      T.i0 = y0; T.i1 = y1; T.i2 = y2; T.i3 = y3; \
      T.thr = (T.v3 <= 0) ? 0.0f : __int_as_float(T.v3) * MLO; \
      T.c1 = 1.0f + T.thr; T.thrga = T.thr * ga_##G; }

    {
        float4 qc = p4[lane];
        float px1 = qc.x - 0.5f * qc.z, py1 = qc.y - 0.5f * qc.w;
        float px2 = qc.x + 0.5f * qc.z, py2 = qc.y + 0.5f * qc.w;
        float pa = __fmul_rn(px2 - px1, py2 - py1);
        PIOU(0, vb0) PIOU(1, vb1)
        PRIME(t0, vb0, 0) PRIME(t1, vb1, 1)
    }

    // ---- STREAM (j = 1..63) ----
#define COMP(T, G, IN, TR) \
    float IN; bool TR; \
    { float ltx = fmaxf(gx1_##G, px1), lty = fmaxf(gy1_##G, py1); \
      float rbx = fminf(gx2_##G, px2), rby = fminf(gy2_##G, py2); \
      float wc = fmaxf(rbx - ltx, 0.0f), hc = fmaxf(rby - lty, 0.0f); \
      IN = __fmul_rn(wc, hc); \
      TR = IN * T.c1 > __fmaf_rn(T.thr, pa, T.thrga); }

    // Rare path: parallel exec-masked exact div, readlane-ordered insert.
#define MERGE(T, G, MK, IN, TR) \
    if (MK) { \
      float iouv = 0.0f; \
      if (TR) { float uu = fmaxf((ga_##G + pa) - IN, 1e-9f); iouv = IN / uu; } \
      unsigned long long mk = MK; \
      do { \
        int l = __ffsll((unsigned long long)mk) - 1; mk &= mk - 1; \
        int vb = (int)__builtin_amdgcn_readlane(__float_as_int(iouv), l); \
        if (vb > T.v3) {                          /* strict: exact tie rule */ \
          int n = nb + l; \
          bool c2 = vb > T.v2, c1c = vb > T.v1, c0 = vb > T.v0; \
          T.v3 = c2 ? T.v2 : vb;                T.i3 = c2 ? T.i2 : n; \
          T.v2 = c2 ? (c1c ? T.v1 : vb) : T.v2; T.i2 = c2 ? (c1c ? T.i1 : n) : T.i2; \
          T.v1 = c1c ? (c0 ? T.v0 : vb) : T.v1; T.i1 = c1c ? (c0 ? T.i0 : n) : T.i1; \
          T.v0 = c0 ? vb : T.v0;                T.i0 = c0 ? n : T.i0; \
        } \
      } while (mk); \
      T.thr = (T.v3 == 0) ? 0.0f : __int_as_float(T.v3) * MLO; \
      T.c1 = 1.0f + T.thr; T.thrga = T.thr * ga_##G; \
    }

    float4 qn = p4[64 + lane];
    for (int j = 1; j < 64; ++j) {
        float4 qc = qn;
        int jn = (j < 63) ? j + 1 : 63;
        qn = p4[jn * 64 + lane];           // prefetch next tile (L2-resident)
        float px1 = qc.x - 0.5f * qc.z, py1 = qc.y - 0.5f * qc.w;
        float px2 = qc.x + 0.5f * qc.z, py2 = qc.y + 0.5f * qc.w;
        float pa = __fmul_rn(px2 - px1, py2 - py1);
        const int nb = j * 64;
        COMP(t0, 0, in0, tr0)
        COMP(t1, 1, in1, tr1)
        unsigned long long mk0 = __ballot(tr0), mk1 = __ballot(tr1);
        if (mk0 | mk1) {                   // single rare branch per iter
            MERGE(t0, 0, mk0, in0, tr0)
            MERGE(t1, 1, mk1, in1, tr1)
        }
    }

    if (lane == 0) {
        float* pi = out + (size_t)BB * MM * KK;
        float* gi = out + (size_t)2 * BB * MM * KK;
#define WOUT(T, G) \
        { int gm = b * MM + mbase + G; \
          float gmxf = __int_as_float(T.v0); \
          topv[gm * KK + 0] = gmxf; \
          topv[gm * KK + 1] = __int_as_float(T.v1); \
          topv[gm * KK + 2] = __int_as_float(T.v2); \
          topv[gm * KK + 3] = __int_as_float(T.v3); \
          pi[gm * KK + 0] = (float)T.i0; pi[gm * KK + 1] = (float)T.i1; \
          pi[gm * KK + 2] = (float)T.i2; pi[gm * KK + 3] = (float)T.i3; \
          float fm = (float)(mbase + G); \
          gi[gm * KK + 0] = fm; gi[gm * KK + 1] = fm; \
          gi[gm * KK + 2] = fm; gi[gm * KK + 3] = fm; \
          pack[gm * 2 + 0] = make_float4(gx1_##G, gy1_##G, gx2_##G, gy2_##G); \
          float gthr = (gmxf > 0.0f) ? gmxf * MLO : -1.0f; \
          pack[gm * 2 + 1] = make_float4(ga_##G, gmxf, gthr, 0.0f); \
          counts[gm] = 0; }
        WOUT(t0, 0) WOUT(t1, 1)
    }
}

// ---------------------------------------------------------------------------
// Kernel B: per-proposal argmax over gts (first-max), fg/lq, count scatter.
// One thread per proposal, FULL 512-gt loop (no split: the per-lane sparse
// trigger needs a long stream to amortize warm-up -- quarter splits re-warm
// 4x, round-11 analysis). Per step: packed gt data via uniform s_loads (no
// VALU conversion -- precomputed in kernA), 16-op branchless trigger
//   IN*(1+tmin) > tmin*s,  tmin = min(best*MLO, gthr_m)
// covering BOTH argmax-update (iou > best) and lq (iou == gmx, since
// gthr < gmx) conservatively; gthr = -1 sentinel for gmx==0 rows makes them
// always-trigger (exact all-lq semantics). Exact IEEE div + state updates
// (~19 ops) only under the per-lane branch (~38% wave taken-rate expected).
// ---------------------------------------------------------------------------
__global__ __launch_bounds__(256) void kernB(const float* __restrict__ pr,
                                             const float4* __restrict__ pack,
                                             int* __restrict__ counts) {
    const int b = blockIdx.x >> 4;         // 16 blocks per batch (4096/256)
    const int nblk = blockIdx.x & 15;
    const int tid = threadIdx.x;

    const int n = nblk * 256 + tid;
    float4 qq = ((const float4*)(pr + (size_t)b * NN * 4))[n];
    const float qx1 = qq.x - 0.5f * qq.z, qy1 = qq.y - 0.5f * qq.w;
    const float qx2 = qq.x + 0.5f * qq.z, qy2 = qq.y + 0.5f * qq.w;
    const float pa = __fmul_rn(qx2 - qx1, qy2 - qy1);

    const float4* gp = pack + (size_t)b * MM * 2;

    // init (0, 0) is exact: iou >= 0; all-zero row -> argmax = 0.
    float best = 0.0f, thr = 0.0f;
    int bidx = 0;
    bool lq = false;

    #pragma unroll 4
    for (int m = 0; m < MM; ++m) {
        float4 gb = gp[m * 2];             // uniform -> s_load (xyxy)
        float4 ax = gp[m * 2 + 1];         // uniform -> s_load (ar, gmx, gthr)
        float ltx = fmaxf(gb.x, qx1), lty = fmaxf(gb.y, qy1);
        float rbx = fminf(gb.z, qx2), rby = fminf(gb.w, qy2);
        float w = fmaxf(rbx - ltx, 0.0f), h = fmaxf(rby - lty, 0.0f);
        float IN = __fmul_rn(w, h);
        float s = ax.x + pa;
        float tmin = fminf(thr, ax.z);
        if (IN * (1.0f + tmin) > tmin * s) {   // conservative, no misses
            float u = fmaxf(s - IN, 1e-9f);
            float iou = IN / u;            // exact IEEE: rounded-tie semantics
            bool c = iou > best;           // first max kept, like jnp.argmax
            best = c ? iou : best;
            bidx = c ? m : bidx;
            lq = lq || (iou == ax.y);      // exact equality vs per-gt max
            thr = best * MLO;
        }
    }

    if (__float_as_int(best) >= FG_BITS || lq) {
        atomicAdd(&counts[b * MM + bidx], 1);
    }
}

// ---------------------------------------------------------------------------
// Kernel C: write scores + valid sections (pr_inds/gt_inds done by kernA).
// ---------------------------------------------------------------------------
__global__ __launch_bounds__(256) void kernC(const float* __restrict__ topv,
                                             const int* __restrict__ counts,
                                             float* __restrict__ out) {
    const int gm = blockIdx.x * 256 + threadIdx.x;   // 0 .. B*M-1
    if (gm >= BB * MM) return;
    const int cnt = counts[gm];
    float* sc = out;
    float* va = out + (size_t)3 * BB * MM * KK;
    #pragma unroll
    for (int k = 0; k < KK; ++k) {
        const bool val = k < cnt;
        sc[gm * KK + k] = val ? topv[gm * KK + k] : 0.0f;
        va[gm * KK + k] = val ? 1.0f : 0.0f;
    }
}

extern "C" void kernel_launch(void* const* d_in, const int* in_sizes, int n_in,
                              void* d_out, int out_size, void* d_ws, size_t ws_size,
                              hipStream_t stream) {
    const float* gt = (const float*)d_in[0];   // [B,M,4] cxcywh
    const float* pr = (const float*)d_in[1];   // [B,N,4] cxcywh
    // d_in[2] (gt_labels) is unused by the reference outputs.
    float* out = (float*)d_out;
    char* ws = (char*)d_ws;

    int*    counts = (int*)(ws);                    //  64 KB @ 0
    float*  topv   = (float*)(ws + (1 << 16));      // 256 KB @ 64K
    float4* pack   = (float4*)(ws + (5 << 16));     // 512 KB @ 320K (tot 832K)

    kernA<<<BB * (MM / 8), 256, 0, stream>>>(gt, pr, topv, pack, counts, out);
    kernB<<<BB * (NN / 256), 256, 0, stream>>>(pr, pack, counts);
    kernC<<<(BB * MM + 255) / 256, 256, 0, stream>>>(topv, counts, out);
}

// Round 14
// 115.025 us; speedup vs baseline: 1.4480x; 1.4480x over previous
//
#include <hip/hip_runtime.h>

#define BB 32
#define MM 512
#define NN 4096
#define KK 4
#define MLO 0.999998f         // 1 - 2^-19: trigger margin, no false negatives
#define FG_BITS 0x3F19999A    // bit pattern of 0.6f

// All IoU values are >= +0.0f, so float ordering == signed-int ordering on the
// bit patterns, with -1 (int) as a below-everything sentinel.

__device__ __forceinline__ int rfl(int x) {
    return __builtin_amdgcn_readfirstlane(x);
}

__device__ __forceinline__ bool beatsI(int v1, int i1, int v2, int i2) {
    // total order: value descending, index ascending (JAX top_k tie-break)
    return (v1 > v2) || (v1 == v2 && i1 < i2);
}

// branchless compare-exchange keeping the winner in (av,ai)
#define CE(av, ai, bv, bi)                                        \
    {                                                             \
        bool _s = beatsI(bv, bi, av, ai);                         \
        int _mv = _s ? bv : av, _nv = _s ? av : bv;               \
        int _mi = _s ? bi : ai, _ni = _s ? ai : bi;               \
        av = _mv; bv = _nv; ai = _mi; bi = _ni;                   \
    }

struct T4 { int v0, v1, v2, v3; int i0, i1, i2, i3; float thr, c1, thrga; };

// ---------------------------------------------------------------------------
// Kernel A (round-11/13 structure, ~50us measured): per-gt top-4 (exact JAX
// top_k tie-break); writes pr_inds/gt_inds straight to d_out, topv + packed
// gt data {xyxy}, {area, gmx, gthr} to ws, zeroes counts. 2 gts/wave, no
// LDS, L2-resident proposal stream, PRIME butterfly + sparse mult-trigger
// STREAM + parallel-masked-div MERGE.
// ---------------------------------------------------------------------------
__global__ __launch_bounds__(256) void kernA(const float* __restrict__ gt,
                                             const float* __restrict__ pr,
                                             float* __restrict__ topv,
                                             float4* __restrict__ pack,
                                             int* __restrict__ counts,
                                             float* __restrict__ out) {
    const int b = blockIdx.x >> 6;         // 64 blocks per batch (512 gts / 8)
    const int mblk = blockIdx.x & 63;
    const int tid = threadIdx.x;
    const int wave = rfl(tid >> 6), lane = tid & 63;
    const int mbase = mblk * 8 + wave * 2; // 2 gts per wave
    const float4* g4 = (const float4*)(gt + (size_t)b * MM * 4);
    const float4* p4 = (const float4*)(pr + (size_t)b * NN * 4);

#define GTDEF(G) \
    float gx1_##G, gy1_##G, gx2_##G, gy2_##G, ga_##G; \
    { float4 gg = g4[mbase + G]; \
      float x1 = gg.x - 0.5f * gg.z, y1 = gg.y - 0.5f * gg.w; \
      float x2 = gg.x + 0.5f * gg.z, y2 = gg.y + 0.5f * gg.w; \
      gx1_##G = x1; gy1_##G = y1; gx2_##G = x2; gy2_##G = y2; \
      ga_##G = __fmul_rn(x2 - x1, y2 - y1); }

    GTDEF(0) GTDEF(1)

    T4 t0, t1;

    // ---- PRIME (j = 0): exact iou all lanes, butterfly -> uniform top-4 ----
#define PIOU(G, VB) \
    int VB; \
    { float ltx = fmaxf(gx1_##G, px1), lty = fmaxf(gy1_##G, py1); \
      float rbx = fminf(gx2_##G, px2), rby = fminf(gy2_##G, py2); \
      float wc = fmaxf(rbx - ltx, 0.0f), hc = fmaxf(rby - lty, 0.0f); \
      float inter = __fmul_rn(wc, hc); \
      float u = fmaxf((ga_##G + pa) - inter, 1e-9f); \
      VB = __float_as_int(inter / u); }

#define PRIME(T, VB, G) \
    { int x0 = VB, x1 = -1, x2 = -1, x3 = -1; \
      int y0 = lane, y1 = 0x7fffffff, y2 = 0x7fffffff, y3 = 0x7fffffff; \
      for (int off = 1; off < 64; off <<= 1) { \
        int b0 = __shfl_xor(x0, off), b1 = __shfl_xor(x1, off); \
        int b2 = __shfl_xor(x2, off), b3 = __shfl_xor(x3, off); \
        int j0 = __shfl_xor(y0, off), j1 = __shfl_xor(y1, off); \
        int j2 = __shfl_xor(y2, off), j3 = __shfl_xor(y3, off); \
        int z4 = b3, z5 = b2, z6 = b1, z7 = b0; \
        int w4 = j3, w5 = j2, w6 = j1, w7 = j0; \
        CE(x0, y0, z4, w4); CE(x1, y1, z5, w5); \
        CE(x2, y2, z6, w6); CE(x3, y3, z7, w7); \
        CE(x0, y0, x2, y2); CE(x1, y1, x3, y3); \
        CE(x0, y0, x1, y1); CE(x2, y2, x3, y3); \
      } \
      T.v0 = x0; T.v1 = x1; T.v2 = x2; T.v3 = x3; \
      T.i0 = y0; T.i1 = y1; T.i2 = y2; T.i3 = y3; \
      T.thr = (T.v3 <= 0) ? 0.0f : __int_as_float(T.v3) * MLO; \
      T.c1 = 1.0f + T.thr; T.thrga = T.thr * ga_##G; }

    {
        float4 qc = p4[lane];
        float px1 = qc.x - 0.5f * qc.z, py1 = qc.y - 0.5f * qc.w;
        float px2 = qc.x + 0.5f * qc.z, py2 = qc.y + 0.5f * qc.w;
        float pa = __fmul_rn(px2 - px1, py2 - py1);
        PIOU(0, vb0) PIOU(1, vb1)
        PRIME(t0, vb0, 0) PRIME(t1, vb1, 1)
    }

    // ---- STREAM (j = 1..63) ----
#define COMP(T, G, IN, TR) \
    float IN; bool TR; \
    { float ltx = fmaxf(gx1_##G, px1), lty = fmaxf(gy1_##G, py1); \
      float rbx = fminf(gx2_##G, px2), rby = fminf(gy2_##G, py2); \
      float wc = fmaxf(rbx - ltx, 0.0f), hc = fmaxf(rby - lty, 0.0f); \
      IN = __fmul_rn(wc, hc); \
      TR = IN * T.c1 > __fmaf_rn(T.thr, pa, T.thrga); }

    // Rare path: parallel exec-masked exact div, readlane-ordered insert.
#define MERGE(T, G, MK, IN, TR) \
    if (MK) { \
      float iouv = 0.0f; \
      if (TR) { float uu = fmaxf((ga_##G + pa) - IN, 1e-9f); iouv = IN / uu; } \
      unsigned long long mk = MK; \
      do { \
        int l = __ffsll((unsigned long long)mk) - 1; mk &= mk - 1; \
        int vb = (int)__builtin_amdgcn_readlane(__float_as_int(iouv), l); \
        if (vb > T.v3) {                          /* strict: exact tie rule */ \
          int n = nb + l; \
          bool c2 = vb > T.v2, c1c = vb > T.v1, c0 = vb > T.v0; \
          T.v3 = c2 ? T.v2 : vb;                T.i3 = c2 ? T.i2 : n; \
          T.v2 = c2 ? (c1c ? T.v1 : vb) : T.v2; T.i2 = c2 ? (c1c ? T.i1 : n) : T.i2; \
          T.v1 = c1c ? (c0 ? T.v0 : vb) : T.v1; T.i1 = c1c ? (c0 ? T.i0 : n) : T.i1; \
          T.v0 = c0 ? vb : T.v0;                T.i0 = c0 ? n : T.i0; \
        } \
      } while (mk); \
      T.thr = (T.v3 == 0) ? 0.0f : __int_as_float(T.v3) * MLO; \
      T.c1 = 1.0f + T.thr; T.thrga = T.thr * ga_##G; \
    }

    float4 qn = p4[64 + lane];
    for (int j = 1; j < 64; ++j) {
        float4 qc = qn;
        int jn = (j < 63) ? j + 1 : 63;
        qn = p4[jn * 64 + lane];           // prefetch next tile (L2-resident)
        float px1 = qc.x - 0.5f * qc.z, py1 = qc.y - 0.5f * qc.w;
        float px2 = qc.x + 0.5f * qc.z, py2 = qc.y + 0.5f * qc.w;
        float pa = __fmul_rn(px2 - px1, py2 - py1);
        const int nb = j * 64;
        COMP(t0, 0, in0, tr0)
        COMP(t1, 1, in1, tr1)
        unsigned long long mk0 = __ballot(tr0), mk1 = __ballot(tr1);
        if (mk0 | mk1) {                   // single rare branch per iter
            MERGE(t0, 0, mk0, in0, tr0)
            MERGE(t1, 1, mk1, in1, tr1)
        }
    }

    if (lane == 0) {
        float* pi = out + (size_t)BB * MM * KK;
        float* gi = out + (size_t)2 * BB * MM * KK;
#define WOUT(T, G) \
        { int gm = b * MM + mbase + G; \
          float gmxf = __int_as_float(T.v0); \
          topv[gm * KK + 0] = gmxf; \
          topv[gm * KK + 1] = __int_as_float(T.v1); \
          topv[gm * KK + 2] = __int_as_float(T.v2); \
          topv[gm * KK + 3] = __int_as_float(T.v3); \
          pi[gm * KK + 0] = (float)T.i0; pi[gm * KK + 1] = (float)T.i1; \
          pi[gm * KK + 2] = (float)T.i2; pi[gm * KK + 3] = (float)T.i3; \
          float fm = (float)(mbase + G); \
          gi[gm * KK + 0] = fm; gi[gm * KK + 1] = fm; \
          gi[gm * KK + 2] = fm; gi[gm * KK + 3] = fm; \
          pack[gm * 2 + 0] = make_float4(gx1_##G, gy1_##G, gx2_##G, gy2_##G); \
          float gthr = (gmxf > 0.0f) ? gmxf * MLO : -1.0f; \
          pack[gm * 2 + 1] = make_float4(ga_##G, gmxf, gthr, 0.0f); \
          counts[gm] = 0; }
        WOUT(t0, 0) WOUT(t1, 1)
    }
}

// ---------------------------------------------------------------------------
// Kernel B: per-proposal argmax over gts (first-max), fg/lq, count scatter.
// Round-8 geometry (best measured: grid 2048 -> 32 waves/CU) + precomputed
// pack staged to LDS (zero per-step conversion) + round-13's field-validated
// per-lane sparse trigger:
//   IN*(1+tmin) > tmin*s,  tmin = min(best*MLO, gthr_m),  s = ar+pa
// covers argmax-update (iou > best) AND lq (iou == gmx) conservatively;
// gthr = -1 sentinel for gmx==0 rows -> always-trigger (exact lq). Exact
// IEEE div + state updates only under the branch. 64 proposals per block;
// wave qtr reduces gts [128q,128q+128) (init (0, m0) exact: iou>=0, strict >
// in m-order preserves jnp.argmax first-max through the quarter merge).
// Broadcast LDS reads (all lanes same m -> no bank conflict), latency
// pipelined across 32 waves/CU -- round-13's stall was 8 waves + serial
// s_load chain, not the trigger.
// ---------------------------------------------------------------------------
__global__ __launch_bounds__(256) void kernB(const float* __restrict__ pr,
                                             const float4* __restrict__ pack,
                                             int* __restrict__ counts) {
    __shared__ float4 sG[MM];              // xyxy, 8 KB
    __shared__ float4 sA[MM];              // (ar, gmx, gthr, 0), 8 KB
    __shared__ int sV[256], sI[256], sL[256];   // 3 KB
    const int b = blockIdx.x >> 6;         // 64 blocks per batch (4096/64)
    const int nblk = blockIdx.x & 63;
    const int tid = threadIdx.x;

    const float4* gp = pack + (size_t)b * MM * 2;
    for (int i = tid; i < MM; i += 256) {
        sG[i] = gp[i * 2];
        sA[i] = gp[i * 2 + 1];
    }

    const int lane = tid & 63;
    const int qtr = tid >> 6;
    const int m0 = qtr * 128;
    const int n = nblk * 64 + lane;
    float4 qq = ((const float4*)(pr + (size_t)b * NN * 4))[n];
    const float qx1 = qq.x - 0.5f * qq.z, qy1 = qq.y - 0.5f * qq.w;
    const float qx2 = qq.x + 0.5f * qq.z, qy2 = qq.y + 0.5f * qq.w;
    const float pa = __fmul_rn(qx2 - qx1, qy2 - qy1);
    __syncthreads();

    float best = 0.0f, thr = 0.0f;
    int bidx = m0;
    bool lq = false;

    #pragma unroll 4
    for (int mm = 0; mm < 128; ++mm) {
        const int m = m0 + mm;
        float4 gb = sG[m];                 // broadcast ds_read_b128
        float4 ax = sA[m];                 // broadcast ds_read_b128
        float ltx = fmaxf(gb.x, qx1), lty = fmaxf(gb.y, qy1);
        float rbx = fminf(gb.z, qx2), rby = fminf(gb.w, qy2);
        float w = fmaxf(rbx - ltx, 0.0f), h = fmaxf(rby - lty, 0.0f);
        float IN = __fmul_rn(w, h);
        float s = ax.x + pa;
        float tmin = fminf(thr, ax.z);
        if (IN * (1.0f + tmin) > tmin * s) {   // conservative, no misses
            float u = fmaxf(s - IN, 1e-9f);
            float iou = IN / u;            // exact IEEE: rounded-tie semantics
            bool c = iou > best;           // first max kept, like jnp.argmax
            best = c ? iou : best;
            bidx = c ? m : bidx;
            lq = lq || (iou == ax.y);      // exact equality vs per-gt max
            thr = best * MLO;
        }
    }

    sV[tid] = __float_as_int(best);
    sI[tid] = bidx;
    sL[tid] = lq ? 1 : 0;
    __syncthreads();

    if (tid < 64) {
        int v = sV[tid], i = sI[tid], L = sL[tid];
        #pragma unroll
        for (int q2 = 1; q2 < 4; ++q2) {
            int v2 = sV[tid + q2 * 64], i2 = sI[tid + q2 * 64];
            L |= sL[tid + q2 * 64];
            bool c = v2 > v;               // strict: lower quarter wins ties
            v = c ? v2 : v;
            i = c ? i2 : i;
        }
        if (v >= FG_BITS || L) {           // int cmp == float cmp (non-neg)
            atomicAdd(&counts[b * MM + i], 1);
        }
    }
}

// ---------------------------------------------------------------------------
// Kernel C: write scores + valid sections (pr_inds/gt_inds done by kernA).
// ---------------------------------------------------------------------------
__global__ __launch_bounds__(256) void kernC(const float* __restrict__ topv,
                                             const int* __restrict__ counts,
                                             float* __restrict__ out) {
    const int gm = blockIdx.x * 256 + threadIdx.x;   // 0 .. B*M-1
    if (gm >= BB * MM) return;
    const int cnt = counts[gm];
    float* sc = out;
    float* va = out + (size_t)3 * BB * MM * KK;
    #pragma unroll
    for (int k = 0; k < KK; ++k) {
        const bool val = k < cnt;
        sc[gm * KK + k] = val ? topv[gm * KK + k] : 0.0f;
        va[gm * KK + k] = val ? 1.0f : 0.0f;
    }
}

extern "C" void kernel_launch(void* const* d_in, const int* in_sizes, int n_in,
                              void* d_out, int out_size, void* d_ws, size_t ws_size,
                              hipStream_t stream) {
    const float* gt = (const float*)d_in[0];   // [B,M,4] cxcywh
    const float* pr = (const float*)d_in[1];   // [B,N,4] cxcywh
    // d_in[2] (gt_labels) is unused by the reference outputs.
    float* out = (float*)d_out;
    char* ws = (char*)d_ws;

    int*    counts = (int*)(ws);                    //  64 KB @ 0
    float*  topv   = (float*)(ws + (1 << 16));      // 256 KB @ 64K
    float4* pack   = (float4*)(ws + (5 << 16));     // 512 KB @ 320K (tot 832K)

    kernA<<<BB * (MM / 8), 256, 0, stream>>>(gt, pr, topv, pack, counts, out);
    kernB<<<BB * (NN / 64), 256, 0, stream>>>(pr, pack, counts);
    kernC<<<(BB * MM + 255) / 256, 256, 0, stream>>>(topv, counts, out);
}